// Round 10
// baseline (39.651 us; speedup 1.0000x reference)
//
#include <hip/hip_runtime.h>
#include <hip/hip_bf16.h>

#define HD   512
#define EPS  1e-5f
#define ASTR 520   // A-tile LDS row stride in shorts

typedef short bf16x8 __attribute__((ext_vector_type(8)));
typedef float f32x4  __attribute__((ext_vector_type(4)));
typedef float f32x4n __attribute__((ext_vector_type(4)));   // native vec for nt builtins

__device__ __forceinline__ float bf2f(unsigned short u) {
    union { unsigned int u32; float f; } c; c.u32 = ((unsigned int)u) << 16; return c.f;
}
__device__ __forceinline__ unsigned short f2bf(float f) {
    __hip_bfloat16 h = __float2bfloat16(f);   // RNE
    return __builtin_bit_cast(unsigned short, h);
}

// ---------------------------------------------------------------------------
// K0: fp = static @ Wf^T + bf   (blocks 0..511, one wave per (b,k) pair)
//     Wob = bf16(Wo)            (blocks 512..639)
// ---------------------------------------------------------------------------
__global__ void k0_fp_conv(const float* __restrict__ sf, const float* __restrict__ Wf,
                           const float* __restrict__ bfv, const float* __restrict__ Wo,
                           float* __restrict__ fp, unsigned short* __restrict__ Wob) {
    int t = threadIdx.x;
    int blk = blockIdx.x;
    if (blk < 512) {
        int pair = blk * 4 + (t >> 6);          // 0..2047
        int b = pair >> 9;                      // /512
        int k = pair & 511;
        int lane = t & 63;
        const float4* s4 = (const float4*)(sf + b * HD + lane * 8);
        const float4* w4 = (const float4*)(Wf + (size_t)k * HD + lane * 8);
        float4 sa = s4[0], sb = s4[1], wa = w4[0], wb = w4[1];
        float p = sa.x*wa.x + sa.y*wa.y + sa.z*wa.z + sa.w*wa.w
                + sb.x*wb.x + sb.y*wb.y + sb.z*wb.z + sb.w*wb.w;
        #pragma unroll
        for (int off = 32; off; off >>= 1) p += __shfl_xor(p, off);
        if (lane == 0) fp[b * HD + k] = p + bfv[k];
    } else {
        int base = (blk - 512) * 2048 + t * 8;  // covers 512*512 = 262144 elems
        float4 a = *(const float4*)(Wo + base);
        float4 c = *(const float4*)(Wo + base + 4);
        union { unsigned short us[8]; uint4 v4; } pk;
        pk.us[0]=f2bf(a.x); pk.us[1]=f2bf(a.y); pk.us[2]=f2bf(a.z); pk.us[3]=f2bf(a.w);
        pk.us[4]=f2bf(c.x); pk.us[5]=f2bf(c.y); pk.us[6]=f2bf(c.z); pk.us[7]=f2bf(c.w);
        *(uint4*)(Wob + base) = pk.v4;
    }
}

// ---------------------------------------------------------------------------
// K1: out1b = bf16(LN(temporal + fp[b]))  -- pure streaming, high TLP.
// grid 1024 x 512 thr (8 waves/block, one wave per row) -> 32 waves/CU,
// fill-kernel-like occupancy for the 16.8 MB read + 8.4 MB write.
// out1b stays cached (L3) for K2's low-latency re-read.
// ---------------------------------------------------------------------------
__global__ __launch_bounds__(512) void k1_ln1(
        const float* __restrict__ temporal, const float* __restrict__ fp,
        const float* __restrict__ g1, const float* __restrict__ b1,
        unsigned short* __restrict__ out1b) {
    int t = threadIdx.x;
    int r = blockIdx.x * 8 + (t >> 6);
    int lane = t & 63;
    int b = r >> 11;                             // 2048 rows per batch
    int c0 = lane * 8;

    const f32x4n* rp = (const f32x4n*)(temporal + (size_t)r * HD + c0);
    f32x4n x0 = __builtin_nontemporal_load(rp);      // streaming, don't pollute L2
    f32x4n x1 = __builtin_nontemporal_load(rp + 1);
    float4 f0  = *(const float4*)(fp + b * HD + c0);
    float4 f1  = *(const float4*)(fp + b * HD + c0 + 4);

    float v[8];
    v[0]=x0[0]+f0.x; v[1]=x0[1]+f0.y; v[2]=x0[2]+f0.z; v[3]=x0[3]+f0.w;
    v[4]=x1[0]+f1.x; v[5]=x1[1]+f1.y; v[6]=x1[2]+f1.z; v[7]=x1[3]+f1.w;
    float s = 0.f, q = 0.f;
    #pragma unroll
    for (int j = 0; j < 8; ++j) { s += v[j]; q += v[j] * v[j]; }
    #pragma unroll
    for (int off = 32; off; off >>= 1) { s += __shfl_xor(s, off); q += __shfl_xor(q, off); }
    float mean = s * (1.f / HD);
    float var  = q * (1.f / HD) - mean * mean;
    float rs   = rsqrtf(var + EPS);

    float4 g1a = *(const float4*)(g1 + c0), g1b = *(const float4*)(g1 + c0 + 4);
    float4 b1a = *(const float4*)(b1 + c0), b1b = *(const float4*)(b1 + c0 + 4);
    union { unsigned short us[8]; uint4 v4; } pk;
    pk.us[0]=f2bf((v[0]-mean)*rs*g1a.x+b1a.x); pk.us[1]=f2bf((v[1]-mean)*rs*g1a.y+b1a.y);
    pk.us[2]=f2bf((v[2]-mean)*rs*g1a.z+b1a.z); pk.us[3]=f2bf((v[3]-mean)*rs*g1a.w+b1a.w);
    pk.us[4]=f2bf((v[4]-mean)*rs*g1b.x+b1b.x); pk.us[5]=f2bf((v[5]-mean)*rs*g1b.y+b1b.y);
    pk.us[6]=f2bf((v[6]-mean)*rs*g1b.z+b1b.z); pk.us[7]=f2bf((v[7]-mean)*rs*g1b.w+b1b.w);
    *(uint4*)(out1b + (size_t)r * HD + c0) = pk.v4;   // cached store: K2 re-reads this
}

// ---------------------------------------------------------------------------
// K2: GEMM (out1b @ Wo^T) + LN2 -> out.  32-row tile, 8 waves, B direct
// global->VGPR with depth-3 prefetch (R9).  As now filled by a short L3-hit
// bf16 copy (32 KB/block) instead of the HBM-latency LN1 phase.
// ---------------------------------------------------------------------------
__global__ __launch_bounds__(512) void k2_gemm_ln2(
        const unsigned short* __restrict__ out1b,
        const unsigned short* __restrict__ Bw,  // Wo bf16 [n][k]
        const float* __restrict__ bo,
        const float* __restrict__ g2, const float* __restrict__ b2,
        float* __restrict__ out) {
    __shared__ unsigned short As[32 * ASTR];        // 33.3 KB, LN1 result (bf16)
    __shared__ float part_s[8][32], part_q[8][32];  // per-wave LN2 partials
    __shared__ float stat_m[32], stat_r[32];

    int t = threadIdx.x;
    int m0 = blockIdx.x * 32;
    int lane = t & 63, w = t >> 6;
    int rl = lane & 15, kl = lane >> 4;

    // ---- B prefetch first (independent of As; 3 k-steps deep) ----
    const unsigned short* Bbase = Bw + (size_t)(w * 64 + rl) * HD + kl * 8;
    bf16x8 bq[3][4];                                 // statically indexed after full unroll
    #pragma unroll
    for (int s3 = 0; s3 < 3; ++s3)
        #pragma unroll
        for (int j = 0; j < 4; ++j)
            bq[s3][j] = *(const bf16x8*)(Bbase + j * 16 * HD + s3 * 32);

    // ---- As fill: 32 rows x 1 KB from out1b (L3/L2-resident) ----
    {
        int row = t >> 4;                            // 0..31
        int cc  = (t & 15) * 32;                     // shorts; 16 thr x 64 B per row
        const unsigned short* src = out1b + (size_t)(m0 + row) * HD + cc;
        #pragma unroll
        for (int j = 0; j < 4; ++j)
            *(uint4*)(&As[row * ASTR + cc + j * 8]) = *(const uint4*)(src + j * 8);
    }
    __syncthreads();                                 // As ready

    // -------- GEMM, B direct global->VGPR, depth-3 prefetch --------
    f32x4 acc[2][4];
    #pragma unroll
    for (int i = 0; i < 2; ++i)
        #pragma unroll
        for (int j = 0; j < 4; ++j) acc[i][j] = (f32x4){0.f, 0.f, 0.f, 0.f};

    #pragma unroll
    for (int step = 0; step < 16; ++step) {
        int kb   = step * 32;
        int slot = step % 3;                         // compile-time after unroll
        bf16x8 a0 = *(const bf16x8*)(&As[rl * ASTR + kb + kl * 8]);
        bf16x8 a1 = *(const bf16x8*)(&As[(rl + 16) * ASTR + kb + kl * 8]);
        #pragma unroll
        for (int j = 0; j < 4; ++j) {
            acc[0][j] = __builtin_amdgcn_mfma_f32_16x16x32_bf16(a0, bq[slot][j], acc[0][j], 0, 0, 0);
            acc[1][j] = __builtin_amdgcn_mfma_f32_16x16x32_bf16(a1, bq[slot][j], acc[1][j], 0, 0, 0);
        }
        if (step + 3 < 16) {                         // refill the just-used slot, 3 ahead
            #pragma unroll
            for (int j = 0; j < 4; ++j)
                bq[slot][j] = *(const bf16x8*)(Bbase + j * 16 * HD + kb + 96);
        }
    }

    // ---------------- LN2 epilogue ----------------
    // C/D layout: col = w*64 + j*16 + rl, row = i*16 + kl*4 + reg
    float bov[4], g2v[4], b2v[4];
    #pragma unroll
    for (int j = 0; j < 4; ++j) {
        int col = w * 64 + j * 16 + rl;
        bov[j] = bo[col]; g2v[j] = g2[col]; b2v[j] = b2[col];
    }
    #pragma unroll
    for (int i = 0; i < 2; ++i)
        #pragma unroll
        for (int r2 = 0; r2 < 4; ++r2) {
            int row = i * 16 + kl * 4 + r2;
            float s = 0.f, q = 0.f;
            #pragma unroll
            for (int j = 0; j < 4; ++j) {
                float o1 = bf2f(As[row * ASTR + w * 64 + j * 16 + rl]);
                float vv = acc[i][j][r2] + bov[j] + o1;   // out1 + proj
                acc[i][j][r2] = vv;
                s += vv; q += vv * vv;
            }
            #pragma unroll
            for (int off = 1; off < 16; off <<= 1) {      // reduce over rl (16-group)
                s += __shfl_xor(s, off); q += __shfl_xor(q, off);
            }
            if (rl == 0) { part_s[w][row] = s; part_q[w][row] = q; }
        }
    __syncthreads();
    if (t < 32) {
        float s = 0.f, q = 0.f;
        #pragma unroll
        for (int ww = 0; ww < 8; ++ww) { s += part_s[ww][t]; q += part_q[ww][t]; }
        float mean = s * (1.f / HD);
        float var  = q * (1.f / HD) - mean * mean;
        stat_m[t] = mean;
        stat_r[t] = rsqrtf(var + EPS);
    }
    __syncthreads();
    #pragma unroll
    for (int i = 0; i < 2; ++i)
        #pragma unroll
        for (int r2 = 0; r2 < 4; ++r2) {
            int row  = i * 16 + kl * 4 + r2;
            float mean = stat_m[row], rs = stat_r[row];
            #pragma unroll
            for (int j = 0; j < 4; ++j) {
                int col = w * 64 + j * 16 + rl;
                out[(size_t)(m0 + row) * HD + col] = (acc[i][j][r2] - mean) * rs * g2v[j] + b2v[j];
            }
        }
}

// ---------------------------------------------------------------------------
extern "C" void kernel_launch(void* const* d_in, const int* in_sizes, int n_in,
                              void* d_out, int out_size, void* d_ws, size_t ws_size,
                              hipStream_t stream) {
    const float* temporal = (const float*)d_in[0];
    const float* sf  = (const float*)d_in[1];
    // d_in[2] = Wt, d_in[3] = bt : provably unused (softmax over j-constant scores -> uniform)
    const float* Wf  = (const float*)d_in[4];
    const float* bfv = (const float*)d_in[5];
    const float* Wo  = (const float*)d_in[6];
    const float* bo  = (const float*)d_in[7];
    const float* g1  = (const float*)d_in[8];
    const float* b1  = (const float*)d_in[9];
    const float* g2  = (const float*)d_in[10];
    const float* b2  = (const float*)d_in[11];

    char* ws = (char*)d_ws;
    float*          fp    = (float*)ws;                               // 8 KB
    unsigned short* Wob   = (unsigned short*)(ws + 8192);             // 512 KB
    unsigned short* out1b = (unsigned short*)(ws + 8192 + 524288);    // 8.4 MB

    k0_fp_conv <<<640,  256, 0, stream>>>(sf, Wf, bfv, Wo, fp, Wob);
    k1_ln1     <<<1024, 512, 0, stream>>>(temporal, fp, g1, b1, out1b);
    k2_gemm_ln2<<<256,  512, 0, stream>>>(out1b, Wob, bo, g2, b2, (float*)d_out);
}